// Round 11
// baseline (218.364 us; speedup 1.0000x reference)
//
#include <hip/hip_runtime.h>

// Register-resident fused-8 Jacobi x2, v13: v5 physics, 64x128 tile.
//  - 10-round data: per-point-step rate ~104-112ps across ALL structures;
//    v5 (8-wave, 2-dispatch, scalar lanes, 48-float state) was the most
//    saturated (VALU 55%) and bench-best (196.06us). Fused-16 variants
//    traded traffic for sync/latency exposure; net zero. gfx950 unified
//    VGPR/AGPR file means the "AGPR tax" theory (v9/v11/v12) was phantom.
//  - v13 = v5 verbatim mechanics, retiled: 1024 thr = 16 waves x 8-row
//    strips, lane = 1 col, tile 64 cols x 128 rows, halo 8, output 48x112.
//    Redundancy 1.90 -> 1.73; blocks/dispatch 3872 -> 1760 (half the
//    per-block prologues); state unchanged (u8 + wN/S/W/E/Fc 40 = 48).
//  - W/E halo via DPP lane+-1 (edge-lane garbage discard-tight: reaches
//    cols 8/55 only at step 9). N/S: in-register within a strip; strip
//    boundary rows via dbuf LDS (2x2x1024 f32 = 16KB), one barrier/step.
//  - OOB points get all-zero weights -> u'=0 = GD pad; masked tiles write
//    those zeros into ws rows/cols 1022-1023, so dispatch-2's zero-padded
//    1024-stride reads are self-consistent (v5-verified scheme).

namespace {
constexpr int    G    = 1024, Ni = 1022;
constexpr int    TOX  = 48, TOY = 112, HALO = 8;   // tile 64 x 128
constexpr size_t IMG_K = (size_t)G * G;
constexpr size_t IMG_P = (size_t)Ni * Ni;
constexpr size_t WSTR  = 1024;
constexpr size_t IMG_W = (size_t)1024 * 1024;
constexpr float  H2 = (float)(1.0 / (1023.0 * 1023.0));
}

__device__ __forceinline__ float frcp(float x) { return __builtin_amdgcn_rcpf(x); }

// lane l <- lane l-1 (wave_shr1); shifted-in lane gets 0 (bound_ctrl)
__device__ __forceinline__ float lane_shr1(float x) {
    return __builtin_bit_cast(float,
        __builtin_amdgcn_update_dpp(0, __builtin_bit_cast(int, x), 0x138, 0xF, 0xF, true));
}
// lane l <- lane l+1 (wave_shl1)
__device__ __forceinline__ float lane_shl1(float x) {
    return __builtin_bit_cast(float,
        __builtin_amdgcn_update_dpp(0, __builtin_bit_cast(int, x), 0x130, 0xF, 0xF, true));
}

template<bool FIRST, bool LAST>
__global__ __launch_bounds__(1024)
void jac8(const float* __restrict__ usrc, float* __restrict__ udst,
          const float* __restrict__ kap,  const float* __restrict__ fin)
{
    __shared__ float ex[2][2][1024];              // [buf][top/bot][tid] = 16 KB

    const int tid = threadIdx.x;
    const int w = tid >> 6, l = tid & 63;         // wave id (0..15), lane id
    const int bx = blockIdx.x, by = blockIdx.y, b = blockIdx.z;
    const int X0 = bx * TOX - HALO, Y0 = by * TOY - HALO;
    const int gx  = X0 + l;                       // this lane's column
    const int gy0 = Y0 + 8 * w;                   // wave's first row

    const float* kB = kap + (size_t)b * IMG_K;
    const float* fB = fin + (size_t)b * IMG_K;
    const bool fast = (bx >= 1) && (bx <= 20) && (by >= 1) && (by <= 8);

    // ---- stage kappa (10 rows), f (8 rows), u (8 rows) straight to regs ----
    float ka[10], fv[8], u[8];
    if (fast) {                                   // every access in-bounds
        const float* kp = kB + (size_t)gy0 * G + (gx + 1);
        #pragma unroll
        for (int i = 0; i < 10; ++i) ka[i] = kp[(size_t)i * G];
        const float* fp = fB + (size_t)(gy0 + 1) * G + (gx + 1);
        #pragma unroll
        for (int r = 0; r < 8; ++r) fv[r] = fp[(size_t)r * G];
        if (FIRST) {
            const float* uS = usrc + (size_t)b * IMG_P + (size_t)gy0 * Ni + gx;
            #pragma unroll
            for (int r = 0; r < 8; ++r) u[r] = uS[(size_t)r * Ni];
        } else {
            const float* uS = usrc + (size_t)b * IMG_W + (size_t)gy0 * WSTR + gx;
            #pragma unroll
            for (int r = 0; r < 8; ++r) u[r] = uS[(size_t)r * WSTR];
        }
    } else {
        const int cx = gx + 1;
        #pragma unroll
        for (int i = 0; i < 10; ++i) {
            const int ry = gy0 + i;
            ka[i] = ((unsigned)ry < (unsigned)G && (unsigned)cx < (unsigned)G)
                  ? kB[(size_t)ry * G + cx] : 0.0f;
        }
        #pragma unroll
        for (int r = 0; r < 8; ++r) {
            const int ry = gy0 + 1 + r;
            fv[r] = ((unsigned)ry < (unsigned)G && (unsigned)cx < (unsigned)G)
                  ? fB[(size_t)ry * G + cx] : 0.0f;
        }
        if (FIRST) {
            const float* uS = usrc + (size_t)b * IMG_P;
            #pragma unroll
            for (int r = 0; r < 8; ++r) {
                const int gy = gy0 + r;
                u[r] = ((unsigned)gy < (unsigned)Ni && (unsigned)gx < (unsigned)Ni)
                     ? uS[(size_t)gy * Ni + gx] : 0.0f;
            }
        } else {
            const float* uS = usrc + (size_t)b * IMG_W;
            #pragma unroll
            for (int r = 0; r < 8; ++r) {
                const int gy = gy0 + r;
                u[r] = ((unsigned)gy < 1024u && (unsigned)gx < 1024u)
                     ? uS[(size_t)gy * WSTR + gx] : 0.0f;
            }
        }
    }

    // ---- iteration-invariant weights; explicit wE, no masks ----
    float wN[8], wS[8], wW[8], wE[8], Fc[8];
    if (fast) {
        #pragma unroll
        for (int r = 0; r < 8; ++r) {
            const float kn = ka[r], kc = ka[r + 1], ks = ka[r + 2];
            const float kw = lane_shr1(kc), ke = lane_shl1(kc);   // edge lanes: halo-safe garbage
            const float inv = frcp(2.0f * kc + 0.5f * (kn + ks + kw + ke));
            wN[r] = 0.5f * (kc + kn) * inv;
            wS[r] = 0.5f * (kc + ks) * inv;
            wW[r] = 0.5f * (kc + kw) * inv;
            wE[r] = 0.5f * (kc + ke) * inv;
            Fc[r] = fv[r] * H2 * inv;
        }
    } else {
        #pragma unroll
        for (int r = 0; r < 8; ++r) {
            const float kn = ka[r], kc = ka[r + 1], ks = ka[r + 2];
            const float kw = lane_shr1(kc), ke = lane_shl1(kc);
            const float inv = frcp(2.0f * kc + 0.5f * (kn + ks + kw + ke));
            const int gy = gy0 + r;
            const bool dv = ((unsigned)gy < (unsigned)Ni) && ((unsigned)gx < (unsigned)Ni);
            wN[r] = dv ? 0.5f * (kc + kn) * inv : 0.0f;
            wS[r] = dv ? 0.5f * (kc + ks) * inv : 0.0f;
            wW[r] = dv ? 0.5f * (kc + kw) * inv : 0.0f;
            wE[r] = dv ? 0.5f * (kc + ke) * inv : 0.0f;
            Fc[r] = dv ? fv[r] * H2 * inv : 0.0f;
        }
    }

    // ---- 8 steps; N/S in registers, W/E via DPP, strip edges via dbuf LDS ----
    const int iN = (w > 0)  ? tid - 64 : tid;     // wave w-1's bottom row (clamp: halo-safe)
    const int iS = (w < 15) ? tid + 64 : tid;     // wave w+1's top row
    #pragma unroll
    for (int t = 0; t < 8; ++t) {
        float* top = ex[t & 1][0];
        float* bot = ex[t & 1][1];
        top[tid] = u[0];
        bot[tid] = u[7];
        __syncthreads();
        const float hN = bot[iN];
        const float hS = top[iS];
        const float o0 = u[0], o1 = u[1], o6 = u[6], o7 = u[7];
        // inner rows 1..6: pure registers (halo-read latency hides under these)
        float prev = o0;
        #pragma unroll
        for (int r = 1; r < 7; ++r) {
            const float cur = u[r], nxt = u[r + 1];
            const float uW = lane_shr1(cur), uE = lane_shl1(cur);
            u[r] = fmaf(wN[r], prev,
                   fmaf(wS[r], nxt,
                   fmaf(wW[r], uW,
                   fmaf(wE[r], uE, Fc[r]))));
            prev = cur;
        }
        {   // row 0 (needs hN; S neighbor is old u[1])
            const float uW = lane_shr1(o0), uE = lane_shl1(o0);
            u[0] = fmaf(wN[0], hN,
                   fmaf(wS[0], o1,
                   fmaf(wW[0], uW,
                   fmaf(wE[0], uE, Fc[0]))));
        }
        {   // row 7 (needs hS; N neighbor is old u[6])
            const float uW = lane_shr1(o7), uE = lane_shl1(o7);
            u[7] = fmaf(wN[7], o6,
                   fmaf(wS[7], hS,
                   fmaf(wW[7], uW,
                   fmaf(wE[7], uE, Fc[7]))));
        }
    }

    // ---- store valid region rel [8,120)x[8,56): waves 1..14, lanes 8..55 ----
    if (w >= 1 && w < 15 && l >= 8 && l < 56) {
        if (LAST) {
            float* oB = udst + (size_t)b * IMG_P;
            #pragma unroll
            for (int r = 0; r < 8; ++r) {
                const int gy = gy0 + r;
                if ((unsigned)gy < (unsigned)Ni && (unsigned)gx < (unsigned)Ni)
                    oB[(size_t)gy * Ni + gx] = u[r];
            }
        } else {
            float* oB = udst + (size_t)b * IMG_W;
            #pragma unroll
            for (int r = 0; r < 8; ++r) {
                const int gy = gy0 + r;
                if ((unsigned)gy < 1024u && (unsigned)gx < 1024u)
                    oB[(size_t)gy * WSTR + gx] = u[r];
            }
        }
    }
}

extern "C" void kernel_launch(void* const* d_in, const int* in_sizes, int n_in,
                              void* d_out, int out_size, void* d_ws, size_t ws_size,
                              hipStream_t stream)
{
    const float* pre = (const float*)d_in[0];
    const float* f   = (const float*)d_in[1];
    const float* kap = (const float*)d_in[2];
    float* out = (float*)d_out;
    float* ws  = (float*)d_ws;                 // needs 8*1024*1024*4 = 33.6 MB

    dim3 blk(1024, 1, 1);
    dim3 grd((Ni + TOX - 1) / TOX, (Ni + TOY - 1) / TOY, 8);   // 22 x 10 x 8

    jac8<true,  false><<<grd, blk, 0, stream>>>(pre, ws,  kap, f);
    jac8<false, true ><<<grd, blk, 0, stream>>>(ws,  out, kap, f);
}